// Round 9
// baseline (4352.107 us; speedup 1.0000x reference)
//
#include <hip/hip_runtime.h>
#include <hip/hip_cooperative_groups.h>
#include <math.h>

namespace cg = cooperative_groups;

// Sinkhorn loss, n=m=8192, K=32, eps=1, L=10 iterations.
// Round 9: R5 geometry (proven 406us: 64-row waves, 256-row WGs, NPS=32,
// VGPR<=128 via launch_bounds(256,4), no spill) FUSED into one cooperative
// kernel: prep -> 20 passes (grid.sync between) -> loss -> reduce.
// Removes ~23 dispatch boundaries (launch overhead, tail drain, per-kernel
// cold starts — R5 pass0 measured 120-170us cold) and keeps splits/psums
// L2-warm across passes. Fallback to the R5 multi-launch path if cooperative
// launch is rejected.
//   z = l2e*2*x.y via bf16 hi/lo split (3 MFMAs), x pre-scaled by 2*log2e.
//   pass:  psum[slice*n+i] = sum_{j in slice} exp2(z_ij) * pb_j
//   pb_j  = (1/n) / sum_k psum[k*n+j]   (multiplicative bias, reciprocal)
//   loss:  sum_ij fma(z,-ln2,xsq+ysq) * exp2(z) * pa_i * pb_j
// MFMA layouts (m89/m120-verified): A elem j = A[m=lane&15][k=(lane>>4)*8+j];
// C/D: col=lane&15, row=(lane>>4)*4+reg.

#define KDIM 32
#define NPS 32                    // pass column slices (256 cols each)
#define NSL_LOSS 16               // loss column slices (512 cols each)
#define LOG2E 1.44269504088896340736f
#define LN2 0.69314718055994530942f

typedef short short8 __attribute__((ext_vector_type(8)));
typedef float f32x4 __attribute__((ext_vector_type(4)));

__device__ __forceinline__ unsigned short f2bf(float f) {
    unsigned int u = __float_as_uint(f);
    u += 0x7FFF + ((u >> 16) & 1);
    return (unsigned short)(u >> 16);
}
__device__ __forceinline__ float bf2f(unsigned short b) {
    return __uint_as_float(((unsigned int)b) << 16);
}

// ============================================================ device bodies
// Pass body: wave = 64 rows, WG = 256 rows, slice = 256 cols, JT = 8.
__device__ __forceinline__ void pass_body(
    const unsigned short* __restrict__ Ah, const unsigned short* __restrict__ Alo,
    const unsigned short* __restrict__ Bh, const unsigned short* __restrict__ Blo,
    const float* __restrict__ pb_direct, const float* __restrict__ psum_in,
    float* __restrict__ psum_out, int n, float inv_n,
    int rowblk, int slice, int tid,
    float* pbl /*[256]*/, float (*red)[64][17] /*[4][64][17]*/) {
    const int w = tid >> 6, lane = tid & 63;
    const int mrow = lane & 15, quad = lane >> 4, koff = quad * 8;
    const int i0 = (rowblk * 4 + w) * 64;
    const int jbeg = slice * (n / NPS);   // 256 cols

    {   // prologue: multiplicative bias for this slice's 256 cols
        int j = jbeg + tid;
        float b;
        if (pb_direct) {
            b = pb_direct[j];
        } else {
            float s = 0.f;
#pragma unroll 8
            for (int k = 0; k < NPS; ++k) s += psum_in[(size_t)k * n + j];
            b = inv_n / s;
        }
        pbl[tid] = b;
    }

    short8 aH[4], aL[4];
#pragma unroll
    for (int t = 0; t < 4; ++t) {
        size_t rb = (size_t)(i0 + t * 16 + mrow) * KDIM + koff;
        aH[t] = *(const short8*)(Ah + rb);
        aL[t] = *(const short8*)(Alo + rb);
    }
    __syncthreads();

    float rs[16];
#pragma unroll
    for (int q = 0; q < 16; ++q) rs[q] = 0.f;

    auto ldB = [&](int jt, short8* bh, short8* bl, float* pb) {
        const int j0 = jbeg + jt * 32;
#pragma unroll
        for (int u = 0; u < 2; ++u) {
            size_t rb = (size_t)(j0 + u * 16 + mrow) * KDIM + koff;
            bh[u] = *(const short8*)(Bh + rb);
            bl[u] = *(const short8*)(Blo + rb);
            pb[u] = pbl[jt * 32 + u * 16 + mrow];
        }
    };
    auto compute = [&](short8* bh, short8* bl, float* pb) {
#pragma unroll
        for (int t = 0; t < 4; ++t)
#pragma unroll
            for (int u = 0; u < 2; ++u) {
                f32x4 z = {0.f, 0.f, 0.f, 0.f};
                z = __builtin_amdgcn_mfma_f32_16x16x32_bf16(aH[t], bh[u], z, 0, 0, 0);
                z = __builtin_amdgcn_mfma_f32_16x16x32_bf16(aH[t], bl[u], z, 0, 0, 0);
                z = __builtin_amdgcn_mfma_f32_16x16x32_bf16(aL[t], bh[u], z, 0, 0, 0);
#pragma unroll
                for (int r = 0; r < 4; ++r)
                    rs[t * 4 + r] = fmaf(__builtin_amdgcn_exp2f(z[r]), pb[u], rs[t * 4 + r]);
            }
    };

    const int JT = (n / NPS) / 32;   // 8
    short8 bh0[2], bl0[2], bh1[2], bl1[2];
    float pb0v[2], pb1v[2];
    ldB(0, bh0, bl0, pb0v);
    for (int jt = 0; jt < JT; jt += 2) {
        ldB(jt + 1, bh1, bl1, pb1v);
        compute(bh0, bl0, pb0v);
        if (jt + 2 < JT) ldB(jt + 2, bh0, bl0, pb0v);
        compute(bh1, bl1, pb1v);
    }

#pragma unroll
    for (int t = 0; t < 4; ++t)
#pragma unroll
        for (int r = 0; r < 4; ++r)
            red[w][t * 16 + quad * 4 + r][mrow] = rs[t * 4 + r];
    __syncthreads();
    {
        int w2 = tid >> 6, row = tid & 63;
        float s = 0.f;
#pragma unroll
        for (int c = 0; c < 16; ++c) s += red[w2][row][c];
        psum_out[(size_t)slice * n + (rowblk * 4 + w2) * 64 + row] = s;
    }
}

// Loss body: wave = 32 rows, WG = 128 rows, slice = 512 cols, JT = 16.
__device__ __forceinline__ float loss_body(
    const unsigned short* __restrict__ Xh, const unsigned short* __restrict__ Xl,
    const unsigned short* __restrict__ Yh, const unsigned short* __restrict__ Yl,
    const float* __restrict__ apsum, const float* __restrict__ bpsum,
    const float* __restrict__ xsq, const float* __restrict__ ysq,
    int n, float inv_n, int lx, int ly, int tid,
    float* pbL /*[512]*/, float* ysl /*[512]*/, float* pal /*[128]*/,
    float* xsl /*[128]*/, float* red /*[256]*/) {
    const int w = tid >> 6, lane = tid & 63;
    const int mrow = lane & 15, quad = lane >> 4, koff = quad * 8;
    const int i0 = (lx * 4 + w) * 32;
    const int jbeg = ly * (n / NSL_LOSS);   // 512 cols

#pragma unroll
    for (int h = 0; h < 2; ++h) {
        int c = tid + h * 256;
        int j = jbeg + c;
        float s = 0.f;
#pragma unroll 8
        for (int k = 0; k < NPS; ++k) s += bpsum[(size_t)k * n + j];
        pbL[c] = inv_n / s;
        ysl[c] = ysq[j];
    }
    if (tid < 128) {
        int i = lx * 128 + tid;
        float s = 0.f;
#pragma unroll 8
        for (int k = 0; k < NPS; ++k) s += apsum[(size_t)k * n + i];
        pal[tid] = inv_n / s;
        xsl[tid] = xsq[i];
    }

    short8 aH[2], aL[2];
#pragma unroll
    for (int t = 0; t < 2; ++t) {
        size_t rb = (size_t)(i0 + t * 16 + mrow) * KDIM + koff;
        aH[t] = *(const short8*)(Xh + rb);
        aL[t] = *(const short8*)(Xl + rb);
    }
    __syncthreads();

    float pa[8], xs[8];
#pragma unroll
    for (int t = 0; t < 2; ++t)
#pragma unroll
        for (int r = 0; r < 4; ++r) {
            int rl = w * 32 + t * 16 + quad * 4 + r;
            pa[t * 4 + r] = pal[rl];
            xs[t * 4 + r] = xsl[rl];
        }

    float acc = 0.f;

    auto ldB = [&](int jt, short8* bh, short8* bl, float* pb, float* ysv) {
#pragma unroll
        for (int u = 0; u < 2; ++u) {
            int cl = jt * 32 + u * 16 + mrow;
            size_t rb = (size_t)(jbeg + cl) * KDIM + koff;
            bh[u] = *(const short8*)(Yh + rb);
            bl[u] = *(const short8*)(Yl + rb);
            pb[u] = pbL[cl];
            ysv[u] = ysl[cl];
        }
    };
    auto compute = [&](short8* bh, short8* bl, float* pb, float* ysv) {
#pragma unroll
        for (int t = 0; t < 2; ++t)
#pragma unroll
            for (int u = 0; u < 2; ++u) {
                f32x4 z = {0.f, 0.f, 0.f, 0.f};
                z = __builtin_amdgcn_mfma_f32_16x16x32_bf16(aH[t], bh[u], z, 0, 0, 0);
                z = __builtin_amdgcn_mfma_f32_16x16x32_bf16(aH[t], bl[u], z, 0, 0, 0);
                z = __builtin_amdgcn_mfma_f32_16x16x32_bf16(aL[t], bh[u], z, 0, 0, 0);
#pragma unroll
                for (int r = 0; r < 4; ++r) {
                    float dd = z[r];
                    float e = __builtin_amdgcn_exp2f(dd) * (pa[t * 4 + r] * pb[u]);
                    float cst = fmaf(dd, -LN2, xs[t * 4 + r] + ysv[u]);
                    acc = fmaf(cst, e, acc);
                }
            }
    };

    const int JT = (n / NSL_LOSS) / 32;   // 16
    short8 bh0[2], bl0[2], bh1[2], bl1[2];
    float pb0v[2], pb1v[2], ys0v[2], ys1v[2];
    ldB(0, bh0, bl0, pb0v, ys0v);
    for (int jt = 0; jt < JT; jt += 2) {
        ldB(jt + 1, bh1, bl1, pb1v, ys1v);
        compute(bh0, bl0, pb0v, ys0v);
        if (jt + 2 < JT) ldB(jt + 2, bh0, bl0, pb0v, ys0v);
        compute(bh1, bl1, pb1v, ys1v);
    }

    red[tid] = acc;
    __syncthreads();
#pragma unroll
    for (int s = 128; s > 0; s >>= 1) {
        if (tid < s) red[tid] += red[tid + s];
        __syncthreads();
    }
    return red[0];
}

// ============================================================ fused kernel
__global__ __launch_bounds__(256, 4) void sink_fused(
    const float* __restrict__ x, const float* __restrict__ y, int n, float inv_n,
    float* __restrict__ xsq, float* __restrict__ ysq, float* __restrict__ pb0,
    float* __restrict__ apsum, float* __restrict__ bpsum, float* __restrict__ part,
    unsigned short* __restrict__ xh, unsigned short* __restrict__ xl,
    unsigned short* __restrict__ yh, unsigned short* __restrict__ yl,
    float* __restrict__ out) {
    __shared__ float pbl[256];
    __shared__ float red4[4][64][17];
    __shared__ float pbL[512], ysl[512], pal[128], xsl[128];
    __shared__ float lred[256];

    cg::grid_group gg = cg::this_grid();
    const int bid = blockIdx.x;
    const int tid = threadIdx.x;
    const int gtid = bid * 256 + tid;
    const int nelem = n * KDIM;

    // ---------------- phase 0: prep (split + sumsq)
    if (gtid < 2 * nelem / 4) {
        int i4 = gtid * 4;
        const float* src; unsigned short* dh; unsigned short* dl; int off; float sc;
        if (i4 < nelem) { src = x; dh = xh; dl = xl; off = i4; sc = 2.0f * LOG2E; }
        else            { src = y; dh = yh; dl = yl; off = i4 - nelem; sc = 1.0f; }
        float4 v = *(const float4*)(src + off);
        v.x *= sc; v.y *= sc; v.z *= sc; v.w *= sc;
        ushort4 h, l;
        h.x = f2bf(v.x); l.x = f2bf(v.x - bf2f(h.x));
        h.y = f2bf(v.y); l.y = f2bf(v.y - bf2f(h.y));
        h.z = f2bf(v.z); l.z = f2bf(v.z - bf2f(h.z));
        h.w = f2bf(v.w); l.w = f2bf(v.w - bf2f(h.w));
        *(ushort4*)(dh + off) = h;
        *(ushort4*)(dl + off) = l;
    }
    if (gtid < 2 * n) {
        const float* src = (gtid < n) ? x : y;
        int r = (gtid < n) ? gtid : gtid - n;
        const float4* p = (const float4*)(src + (size_t)r * KDIM);
        float s = 0.f;
#pragma unroll
        for (int q = 0; q < 8; ++q) {
            float4 v = p[q];
            s += v.x * v.x + v.y * v.y + v.z * v.z + v.w * v.w;
        }
        if (gtid < n) xsq[r] = s;
        else { ysq[r] = s; pb0[r] = __builtin_amdgcn_exp2f(-LOG2E * s); }
    }
    __threadfence();
    gg.sync();

    // ---------------- phase 1: 20 sinkhorn passes
    const int rowblk = bid & 31;          // 0..31
    const int slice = bid >> 5;           // 0..31
    for (int p = 0; p < 20; ++p) {
        const unsigned short *Ah, *Alo, *Bh, *Blo;
        const float* psum_in; float* psum_out; const float* pbd = nullptr;
        if ((p & 1) == 0) {
            Ah = xh; Alo = xl; Bh = yh; Blo = yl;
            psum_in = bpsum; psum_out = apsum;
            if (p == 0) pbd = pb0;
        } else {
            Ah = yh; Alo = yl; Bh = xh; Blo = xl;
            psum_in = apsum; psum_out = bpsum;
        }
        pass_body(Ah, Alo, Bh, Blo, pbd, psum_in, psum_out, n, inv_n,
                  rowblk, slice, tid, pbl, red4);
        __threadfence();
        gg.sync();
    }

    // ---------------- phase 2: loss -> part[bid]
    {
        const int lx = bid & 63;          // 0..63 row-blocks of 128
        const int ly = bid >> 6;          // 0..15 col-slices of 512
        float v = loss_body(xh, xl, yh, yl, apsum, bpsum, xsq, ysq,
                            n, inv_n, lx, ly, tid, pbL, ysl, pal, xsl, lred);
        if (tid == 0) part[bid] = v;
    }
    __threadfence();
    gg.sync();

    // ---------------- phase 3: final reduce (block 0)
    if (bid == 0) {
        float v = part[tid] + part[tid + 256] + part[tid + 512] + part[tid + 768];
        __syncthreads();                  // lred reuse after loss_body
        lred[tid] = v;
        __syncthreads();
#pragma unroll
        for (int s = 128; s > 0; s >>= 1) {
            if (tid < s) lred[tid] += lred[tid + s];
            __syncthreads();
        }
        if (tid == 0) out[0] = lred[0];
    }
}

// ============================================================ fallback kernels
__global__ void prep_split_k(const float* __restrict__ x, const float* __restrict__ y,
                             int nelem,
                             unsigned short* __restrict__ xh, unsigned short* __restrict__ xl,
                             unsigned short* __restrict__ yh, unsigned short* __restrict__ yl) {
    int i4 = (blockIdx.x * 256 + threadIdx.x) * 4;
    if (i4 >= 2 * nelem) return;
    const float* src; unsigned short* dh; unsigned short* dl; int off; float sc;
    if (i4 < nelem) { src = x; dh = xh; dl = xl; off = i4; sc = 2.0f * LOG2E; }
    else            { src = y; dh = yh; dl = yl; off = i4 - nelem; sc = 1.0f; }
    float4 v = *(const float4*)(src + off);
    v.x *= sc; v.y *= sc; v.z *= sc; v.w *= sc;
    ushort4 h, l;
    h.x = f2bf(v.x); l.x = f2bf(v.x - bf2f(h.x));
    h.y = f2bf(v.y); l.y = f2bf(v.y - bf2f(h.y));
    h.z = f2bf(v.z); l.z = f2bf(v.z - bf2f(h.z));
    h.w = f2bf(v.w); l.w = f2bf(v.w - bf2f(h.w));
    *(ushort4*)(dh + off) = h;
    *(ushort4*)(dl + off) = l;
}

__global__ void prep_sq_k(const float* __restrict__ x, const float* __restrict__ y,
                          int n, float* __restrict__ xsq, float* __restrict__ ysq,
                          float* __restrict__ pb0) {
    int i = blockIdx.x * blockDim.x + threadIdx.x;
    if (i >= 2 * n) return;
    const float* src = (i < n) ? x : y;
    int r = (i < n) ? i : i - n;
    const float4* p = (const float4*)(src + (size_t)r * KDIM);
    float s = 0.f;
#pragma unroll
    for (int q = 0; q < 8; ++q) {
        float4 v = p[q];
        s += v.x * v.x + v.y * v.y + v.z * v.z + v.w * v.w;
    }
    if (i < n) xsq[r] = s;
    else { ysq[r] = s; pb0[r] = __builtin_amdgcn_exp2f(-LOG2E * s); }
}

__global__ __launch_bounds__(256, 4) void sink_pass_k(
    const unsigned short* __restrict__ Ah, const unsigned short* __restrict__ Alo,
    const unsigned short* __restrict__ Bh, const unsigned short* __restrict__ Blo,
    const float* __restrict__ pb_direct, const float* __restrict__ psum_in,
    float* __restrict__ psum_out, int n, float inv_n) {
    __shared__ float pbl[256];
    __shared__ float red4[4][64][17];
    pass_body(Ah, Alo, Bh, Blo, pb_direct, psum_in, psum_out, n, inv_n,
              blockIdx.x, blockIdx.y, threadIdx.x, pbl, red4);
}

__global__ __launch_bounds__(256, 4) void sink_loss_k(
    const unsigned short* __restrict__ Xh, const unsigned short* __restrict__ Xl,
    const unsigned short* __restrict__ Yh, const unsigned short* __restrict__ Yl,
    const float* __restrict__ apsum, const float* __restrict__ bpsum,
    const float* __restrict__ xsq, const float* __restrict__ ysq,
    float* __restrict__ partials, int n, float inv_n) {
    __shared__ float pbL[512], ysl[512], pal[128], xsl[128], lred[256];
    float v = loss_body(Xh, Xl, Yh, Yl, apsum, bpsum, xsq, ysq, n, inv_n,
                        blockIdx.x, blockIdx.y, threadIdx.x, pbL, ysl, pal, xsl, lred);
    if (threadIdx.x == 0) partials[blockIdx.y * gridDim.x + blockIdx.x] = v;
}

__global__ void sink_reduce_k(const float* __restrict__ p, int nb,
                              float* __restrict__ out) {
    __shared__ float red[256];
    int tid = threadIdx.x;
    float v = 0.f;
    for (int i = tid; i < nb; i += 256) v += p[i];
    red[tid] = v;
    __syncthreads();
#pragma unroll
    for (int s = 128; s > 0; s >>= 1) {
        if (tid < s) red[tid] += red[tid + s];
        __syncthreads();
    }
    if (tid == 0) out[0] = red[0];
}

// ============================================================ launch
extern "C" void kernel_launch(void* const* d_in, const int* in_sizes, int n_in,
                              void* d_out, int out_size, void* d_ws, size_t ws_size,
                              hipStream_t stream) {
    const float* x = (const float*)d_in[0];
    const float* y = (const float*)d_in[1];
    int n = in_sizes[0] / KDIM;                       // 8192
    const int nelem = n * KDIM;
    float inv_n = 1.0f / (float)n;

    float* ws = (float*)d_ws;
    float* xsq   = ws;                                //  n
    float* ysq   = ws + n;                            //  n
    float* pb0   = ws + 2 * n;                        //  n
    float* apsum = ws + 3 * n;                        //  NPS*n
    float* bpsum = ws + (3 + NPS) * n;                //  NPS*n
    float* part  = ws + (3 + 2 * NPS) * n;            //  1024 (pad n)
    unsigned short* xh = (unsigned short*)(ws + (4 + 2 * NPS) * n);
    unsigned short* xl = xh + nelem;
    unsigned short* yh = xh + 2 * nelem;
    unsigned short* yl = xh + 3 * nelem;
    float* outp = (float*)d_out;

    void* args[] = {&x, &y, &n, &inv_n, &xsq, &ysq, &pb0, &apsum, &bpsum,
                    &part, &xh, &xl, &yh, &yl, &outp};
    hipError_t err = hipLaunchCooperativeKernel(
        (const void*)sink_fused, dim3(1024), dim3(256), args, 0, stream);

    if (err != hipSuccess) {
        // fallback: R5 multi-launch path (identical math)
        dim3 pgrid(n / 256, NPS);                     // (32, 32)
        dim3 lgrid(n / 128, NSL_LOSS);                // (64, 16)
        prep_split_k<<<(2 * nelem / 4 + 255) / 256, 256, 0, stream>>>(
            x, y, nelem, xh, xl, yh, yl);
        prep_sq_k<<<(2 * n + 255) / 256, 256, 0, stream>>>(x, y, n, xsq, ysq, pb0);
        sink_pass_k<<<pgrid, 256, 0, stream>>>(xh, xl, yh, yl, pb0, nullptr, apsum, n, inv_n);
        sink_pass_k<<<pgrid, 256, 0, stream>>>(yh, yl, xh, xl, nullptr, apsum, bpsum, n, inv_n);
        for (int t = 1; t < 10; ++t) {
            sink_pass_k<<<pgrid, 256, 0, stream>>>(xh, xl, yh, yl, nullptr, bpsum, apsum, n, inv_n);
            sink_pass_k<<<pgrid, 256, 0, stream>>>(yh, yl, xh, xl, nullptr, apsum, bpsum, n, inv_n);
        }
        sink_loss_k<<<lgrid, 256, 0, stream>>>(xh, xl, yh, yl, apsum, bpsum, xsq, ysq, part, n, inv_n);
        sink_reduce_k<<<1, 256, 0, stream>>>(part, (n / 128) * NSL_LOSS, outp);
    }
}

// Round 10
// 423.182 us; speedup vs baseline: 10.2842x; 10.2842x over previous
//
#include <hip/hip_runtime.h>
#include <math.h>

// Sinkhorn loss, n=m=8192, K=32, eps=1, L=10 iterations.
// Round 10: R5 champion structure (406us: 64-row waves, 256-row WGs, NPS=32,
// multi-launch, launch_bounds(256,4), VGPR<=128 no spill) with ONE change:
// the compute loops batch 12 MFMAs back-to-back into a zb[4] register array
// before the exp2 burst (R5's fine-grained 3-MFMA->4-exp pattern stalled the
// wave ~80 cyc per tile on MFMA latency; VGPR=64 showed the compiler kept z
// live ranges tight instead of interleaving).
// R9 lesson: grid.sync+threadfence ~200us/barrier on 8 XCDs (L2 flush) —
// cooperative fusion is structurally wrong; cheap launches are fine.
//   z = l2e*2*x.y via bf16 hi/lo split (3 MFMAs), x pre-scaled by 2*log2e.
//   pass:  psum[slice*n+i] = sum_{j in slice} exp2(z_ij) * pb_j
//   pb_j  = (1/n) / sum_k psum[k*n+j]   (multiplicative bias, reciprocal)
//   loss:  sum_ij fma(z,-ln2,xsq+ysq) * exp2(z) * pa_i * pb_j
// MFMA layouts (m89/m120-verified): A elem j = A[m=lane&15][k=(lane>>4)*8+j];
// C/D: col=lane&15, row=(lane>>4)*4+reg.

#define KDIM 32
#define NPS 32                    // pass column slices (256 cols each)
#define NSL_LOSS 16               // loss column slices (512 cols each)
#define LOG2E 1.44269504088896340736f
#define LN2 0.69314718055994530942f

typedef short short8 __attribute__((ext_vector_type(8)));
typedef float f32x4 __attribute__((ext_vector_type(4)));

__device__ __forceinline__ unsigned short f2bf(float f) {
    unsigned int u = __float_as_uint(f);
    u += 0x7FFF + ((u >> 16) & 1);
    return (unsigned short)(u >> 16);
}
__device__ __forceinline__ float bf2f(unsigned short b) {
    return __uint_as_float(((unsigned int)b) << 16);
}

// ------------------------------------------------------------ prep: hi/lo split
// x side pre-scaled by 2*log2e; y side unscaled.
__global__ void prep_split(const float* __restrict__ x, const float* __restrict__ y,
                           int nelem,
                           unsigned short* __restrict__ xh, unsigned short* __restrict__ xl,
                           unsigned short* __restrict__ yh, unsigned short* __restrict__ yl) {
    int i4 = (blockIdx.x * 256 + threadIdx.x) * 4;
    if (i4 >= 2 * nelem) return;
    const float* src; unsigned short* dh; unsigned short* dl; int off; float sc;
    if (i4 < nelem) { src = x; dh = xh; dl = xl; off = i4; sc = 2.0f * LOG2E; }
    else            { src = y; dh = yh; dl = yl; off = i4 - nelem; sc = 1.0f; }
    float4 v = *(const float4*)(src + off);
    v.x *= sc; v.y *= sc; v.z *= sc; v.w *= sc;
    ushort4 h, l;
    h.x = f2bf(v.x); l.x = f2bf(v.x - bf2f(h.x));
    h.y = f2bf(v.y); l.y = f2bf(v.y - bf2f(h.y));
    h.z = f2bf(v.z); l.z = f2bf(v.z - bf2f(h.z));
    h.w = f2bf(v.w); l.w = f2bf(v.w - bf2f(h.w));
    *(ushort4*)(dh + off) = h;
    *(ushort4*)(dl + off) = l;
}

// ------------------------------------------------------------ prep: row sumsq
__global__ void prep_sq(const float* __restrict__ x, const float* __restrict__ y,
                        int n, float* __restrict__ xsq, float* __restrict__ ysq,
                        float* __restrict__ pb0) {
    int i = blockIdx.x * blockDim.x + threadIdx.x;
    if (i >= 2 * n) return;
    const float* src = (i < n) ? x : y;
    int r = (i < n) ? i : i - n;
    const float4* p = (const float4*)(src + (size_t)r * KDIM);
    float s = 0.f;
#pragma unroll
    for (int q = 0; q < 8; ++q) {
        float4 v = p[q];
        s += v.x * v.x + v.y * v.y + v.z * v.z + v.w * v.w;
    }
    if (i < n) xsq[r] = s;
    else { ysq[r] = s; pb0[r] = __builtin_amdgcn_exp2f(-LOG2E * s); }
}

// ------------------------------------------------------------ pass
// Wave = 64 rows; WG = 4 waves = 256 rows. grid = (n/256, NPS); slice 256 cols.
__global__ __launch_bounds__(256, 4) void sink_pass(
    const unsigned short* __restrict__ Ah, const unsigned short* __restrict__ Alo,
    const unsigned short* __restrict__ Bh, const unsigned short* __restrict__ Blo,
    const float* __restrict__ pb_direct,     // pass 0: exp-bias, else null
    const float* __restrict__ psum_in,       // [slice*n + col]
    float* __restrict__ psum_out, int n, float inv_n) {
    __shared__ float pbl[256];
    __shared__ float red[4][64][17];

    const int tid = threadIdx.x;
    const int w = tid >> 6, lane = tid & 63;
    const int mrow = lane & 15, quad = lane >> 4, koff = quad * 8;
    const int i0 = (blockIdx.x * 4 + w) * 64;
    const int jbeg = blockIdx.y * (n / NPS);   // 256 cols

    {   // prologue: multiplicative bias for this slice's 256 cols
        int j = jbeg + tid;
        float b;
        if (pb_direct) {
            b = pb_direct[j];
        } else {
            float s = 0.f;
#pragma unroll 8
            for (int k = 0; k < NPS; ++k) s += psum_in[(size_t)k * n + j];
            b = inv_n / s;
        }
        pbl[tid] = b;
    }

    short8 aH[4], aL[4];
#pragma unroll
    for (int t = 0; t < 4; ++t) {
        size_t rb = (size_t)(i0 + t * 16 + mrow) * KDIM + koff;
        aH[t] = *(const short8*)(Ah + rb);
        aL[t] = *(const short8*)(Alo + rb);
    }
    __syncthreads();

    float rs[16];
#pragma unroll
    for (int q = 0; q < 16; ++q) rs[q] = 0.f;

    auto ldB = [&](int jt, short8* bh, short8* bl, float* pb) {
        const int j0 = jbeg + jt * 32;
#pragma unroll
        for (int u = 0; u < 2; ++u) {
            size_t rb = (size_t)(j0 + u * 16 + mrow) * KDIM + koff;
            bh[u] = *(const short8*)(Bh + rb);
            bl[u] = *(const short8*)(Blo + rb);
            pb[u] = pbl[jt * 32 + u * 16 + mrow];
        }
    };
    // Batched: 12 MFMAs back-to-back into zb[4], THEN the exp2 burst.
    // (R5 interleaved per-tile and stalled on the 3-chained-MFMA latency.)
    auto compute = [&](short8* bh, short8* bl, float* pb) {
#pragma unroll
        for (int half = 0; half < 2; ++half) {
            f32x4 zb[4];
#pragma unroll
            for (int q = 0; q < 4; ++q) {
                const int t = half * 2 + (q >> 1), u = q & 1;
                f32x4 z = {0.f, 0.f, 0.f, 0.f};
                z = __builtin_amdgcn_mfma_f32_16x16x32_bf16(aH[t], bh[u], z, 0, 0, 0);
                z = __builtin_amdgcn_mfma_f32_16x16x32_bf16(aH[t], bl[u], z, 0, 0, 0);
                z = __builtin_amdgcn_mfma_f32_16x16x32_bf16(aL[t], bh[u], z, 0, 0, 0);
                zb[q] = z;
            }
#pragma unroll
            for (int q = 0; q < 4; ++q) {
                const int t = half * 2 + (q >> 1), u = q & 1;
#pragma unroll
                for (int r = 0; r < 4; ++r)
                    rs[t * 4 + r] = fmaf(__builtin_amdgcn_exp2f(zb[q][r]), pb[u],
                                         rs[t * 4 + r]);
            }
        }
    };

    const int JT = (n / NPS) / 32;   // 8
    short8 bh0[2], bl0[2], bh1[2], bl1[2];
    float pb0v[2], pb1v[2];
    ldB(0, bh0, bl0, pb0v);
    for (int jt = 0; jt < JT; jt += 2) {
        ldB(jt + 1, bh1, bl1, pb1v);
        compute(bh0, bl0, pb0v);
        if (jt + 2 < JT) ldB(jt + 2, bh0, bl0, pb0v);
        compute(bh1, bl1, pb1v);
    }

#pragma unroll
    for (int t = 0; t < 4; ++t)
#pragma unroll
        for (int r = 0; r < 4; ++r)
            red[w][t * 16 + quad * 4 + r][mrow] = rs[t * 4 + r];
    __syncthreads();
    {
        int w2 = tid >> 6, row = tid & 63;
        float s = 0.f;
#pragma unroll
        for (int c = 0; c < 16; ++c) s += red[w2][row][c];
        psum_out[(size_t)blockIdx.y * n + (blockIdx.x * 4 + w2) * 64 + row] = s;
    }
}

// ------------------------------------------------------------ loss
// Wave = 32 rows, WG = 128 rows, grid (n/128, 16), slice 512 cols.
__global__ __launch_bounds__(256, 4) void sink_loss(
    const unsigned short* __restrict__ Xh, const unsigned short* __restrict__ Xl,
    const unsigned short* __restrict__ Yh, const unsigned short* __restrict__ Yl,
    const float* __restrict__ apsum, const float* __restrict__ bpsum,
    const float* __restrict__ xsq, const float* __restrict__ ysq,
    float* __restrict__ partials, int n, float inv_n) {
    __shared__ float pbL[512];
    __shared__ float ysl[512];
    __shared__ float pal[128];
    __shared__ float xsl[128];
    __shared__ float red[256];

    const int tid = threadIdx.x;
    const int w = tid >> 6, lane = tid & 63;
    const int mrow = lane & 15, quad = lane >> 4, koff = quad * 8;
    const int i0 = (blockIdx.x * 4 + w) * 32;
    const int jbeg = blockIdx.y * (n / NSL_LOSS);   // 512 cols

#pragma unroll
    for (int h = 0; h < 2; ++h) {
        int c = tid + h * 256;
        int j = jbeg + c;
        float s = 0.f;
#pragma unroll 8
        for (int k = 0; k < NPS; ++k) s += bpsum[(size_t)k * n + j];
        pbL[c] = inv_n / s;
        ysl[c] = ysq[j];
    }
    if (tid < 128) {
        int i = blockIdx.x * 128 + tid;
        float s = 0.f;
#pragma unroll 8
        for (int k = 0; k < NPS; ++k) s += apsum[(size_t)k * n + i];
        pal[tid] = inv_n / s;
        xsl[tid] = xsq[i];
    }

    short8 aH[2], aL[2];
#pragma unroll
    for (int t = 0; t < 2; ++t) {
        size_t rb = (size_t)(i0 + t * 16 + mrow) * KDIM + koff;
        aH[t] = *(const short8*)(Xh + rb);
        aL[t] = *(const short8*)(Xl + rb);
    }
    __syncthreads();

    float pa[8], xs[8];
#pragma unroll
    for (int t = 0; t < 2; ++t)
#pragma unroll
        for (int r = 0; r < 4; ++r) {
            int rl = w * 32 + t * 16 + quad * 4 + r;
            pa[t * 4 + r] = pal[rl];
            xs[t * 4 + r] = xsl[rl];
        }

    float acc = 0.f;

    auto ldB = [&](int jt, short8* bh, short8* bl, float* pb, float* ysv) {
#pragma unroll
        for (int u = 0; u < 2; ++u) {
            int cl = jt * 32 + u * 16 + mrow;
            size_t rb = (size_t)(jbeg + cl) * KDIM + koff;
            bh[u] = *(const short8*)(Yh + rb);
            bl[u] = *(const short8*)(Yl + rb);
            pb[u] = pbL[cl];
            ysv[u] = ysl[cl];
        }
    };
    // Batched MFMA (all 4 tiles) then the exp/cost burst.
    auto compute = [&](short8* bh, short8* bl, float* pb, float* ysv) {
        f32x4 zb[4];
#pragma unroll
        for (int q = 0; q < 4; ++q) {
            const int t = q >> 1, u = q & 1;
            f32x4 z = {0.f, 0.f, 0.f, 0.f};
            z = __builtin_amdgcn_mfma_f32_16x16x32_bf16(aH[t], bh[u], z, 0, 0, 0);
            z = __builtin_amdgcn_mfma_f32_16x16x32_bf16(aH[t], bl[u], z, 0, 0, 0);
            z = __builtin_amdgcn_mfma_f32_16x16x32_bf16(aL[t], bh[u], z, 0, 0, 0);
            zb[q] = z;
        }
#pragma unroll
        for (int q = 0; q < 4; ++q) {
            const int t = q >> 1, u = q & 1;
#pragma unroll
            for (int r = 0; r < 4; ++r) {
                float dd = zb[q][r];
                float e = __builtin_amdgcn_exp2f(dd) * (pa[t * 4 + r] * pb[u]);
                float cst = fmaf(dd, -LN2, xs[t * 4 + r] + ysv[u]);
                acc = fmaf(cst, e, acc);
            }
        }
    };

    const int JT = (n / NSL_LOSS) / 32;   // 16
    short8 bh0[2], bl0[2], bh1[2], bl1[2];
    float pb0v[2], pb1v[2], ys0v[2], ys1v[2];
    ldB(0, bh0, bl0, pb0v, ys0v);
    for (int jt = 0; jt < JT; jt += 2) {
        ldB(jt + 1, bh1, bl1, pb1v, ys1v);
        compute(bh0, bl0, pb0v, ys0v);
        if (jt + 2 < JT) ldB(jt + 2, bh0, bl0, pb0v, ys0v);
        compute(bh1, bl1, pb1v, ys1v);
    }

    red[tid] = acc;
    __syncthreads();
#pragma unroll
    for (int s = 128; s > 0; s >>= 1) {
        if (tid < s) red[tid] += red[tid + s];
        __syncthreads();
    }
    if (tid == 0) partials[blockIdx.y * gridDim.x + blockIdx.x] = red[0];
}

// ------------------------------------------------------------ final reduce
__global__ void sink_reduce(const float* __restrict__ p, int nb,
                            float* __restrict__ out) {
    __shared__ float red[256];
    int tid = threadIdx.x;
    float v = 0.f;
    for (int i = tid; i < nb; i += 256) v += p[i];
    red[tid] = v;
    __syncthreads();
#pragma unroll
    for (int s = 128; s > 0; s >>= 1) {
        if (tid < s) red[tid] += red[tid + s];
        __syncthreads();
    }
    if (tid == 0) out[0] = red[0];
}

// ------------------------------------------------------------ launch
extern "C" void kernel_launch(void* const* d_in, const int* in_sizes, int n_in,
                              void* d_out, int out_size, void* d_ws, size_t ws_size,
                              hipStream_t stream) {
    const float* x = (const float*)d_in[0];
    const float* y = (const float*)d_in[1];
    const int n = in_sizes[0] / KDIM;                 // 8192
    const int nelem = n * KDIM;
    const float inv_n = 1.0f / (float)n;

    float* ws = (float*)d_ws;
    float* xsq   = ws;                                //  n
    float* ysq   = ws + n;                            //  n
    float* pb0   = ws + 2 * n;                        //  n
    float* apsum = ws + 3 * n;                        //  NPS*n
    float* bpsum = ws + (3 + NPS) * n;                //  NPS*n
    float* part  = ws + (3 + 2 * NPS) * n;            //  1024 (pad n)
    unsigned short* us = (unsigned short*)(ws + (4 + 2 * NPS) * n);
    unsigned short* xh = us;
    unsigned short* xl = us + nelem;
    unsigned short* yh = us + 2 * nelem;
    unsigned short* yl = us + 3 * nelem;

    dim3 pgrid(n / 256, NPS);                         // (32, 32) = 1024 WGs
    dim3 lgrid(n / 128, NSL_LOSS);                    // (64, 16) = 1024 WGs

    prep_split<<<(2 * nelem / 4 + 255) / 256, 256, 0, stream>>>(x, y, nelem, xh, xl, yh, yl);
    prep_sq<<<(2 * n + 255) / 256, 256, 0, stream>>>(x, y, n, xsq, ysq, pb0);

    sink_pass<<<pgrid, 256, 0, stream>>>(xh, xl, yh, yl, pb0, nullptr, apsum, n, inv_n);
    sink_pass<<<pgrid, 256, 0, stream>>>(yh, yl, xh, xl, nullptr, apsum, bpsum, n, inv_n);
    for (int t = 1; t < 10; ++t) {
        sink_pass<<<pgrid, 256, 0, stream>>>(xh, xl, yh, yl, nullptr, bpsum, apsum, n, inv_n);
        sink_pass<<<pgrid, 256, 0, stream>>>(yh, yl, xh, xl, nullptr, apsum, bpsum, n, inv_n);
    }
    sink_loss<<<lgrid, 256, 0, stream>>>(xh, xl, yh, yl, apsum, bpsum, xsq, ysq, part, n, inv_n);
    sink_reduce<<<1, 256, 0, stream>>>(part, (n / 128) * NSL_LOSS, (float*)d_out);
}